// Round 7
// baseline (253.994 us; speedup 1.0000x reference)
//
#include <hip/hip_runtime.h>
#include <hip/hip_bf16.h>

#define NROWS 65536
#define DIM   256
#define NCLS  1000
#define CPAD  1024

typedef __attribute__((ext_vector_type(8))) short bf16x8;   // 8 bf16 = 4 VGPR
typedef __attribute__((ext_vector_type(4))) float f32x4;    // MFMA C/D

// RTNE float -> bf16 bit pattern (finite inputs only)
__device__ inline unsigned short f2bf(float x) {
    unsigned int u = __builtin_bit_cast(unsigned int, x);
    unsigned int lsb = (u >> 16) & 1u;
    u += 0x7fffu + lsb;
    return (unsigned short)(u >> 16);
}

__device__ inline float bf2f(unsigned short u) {
    unsigned int v = ((unsigned int)u) << 16;
    return __builtin_bit_cast(float, v);
}

// async global->LDS, 16 B per lane, dst = wave-uniform base + lane*16
__device__ inline void gload_lds16(const void* g, void* l) {
    __builtin_amdgcn_global_load_lds(
        (const __attribute__((address_space(1))) unsigned int*)g,
        (__attribute__((address_space(3))) unsigned int*)l, 16, 0, 0);
}

// K1: 8 rows per wave, 4-row batched pipeline (R9). Also zeroes the
// sums/counts/acc/done scratch (stream-ordered before K2 needs it).
__global__ __launch_bounds__(256) void k_norm_acc(
    const float* __restrict__ emb, unsigned short* __restrict__ e,
    float* __restrict__ sums, unsigned int* __restrict__ counts,
    float* __restrict__ acc, unsigned int* __restrict__ done)
{
    const int tid = threadIdx.x;
    const int bid = blockIdx.x;
    // zero scratch: 2048 blocks x 128 floats = CPAD*DIM sums
    if (tid < 128) sums[bid * 128 + tid] = 0.0f;
    if (bid < 16 && tid < 64) counts[bid * 64 + tid] = 0u;   // 1024 counts
    if (bid == 0 && tid == 0) { *acc = 0.0f; *done = 0u; }

    const int wave = tid >> 6, lane = tid & 63;
    const int w = bid * 4 + wave;                 // 8192 waves, 8 rows each

    #pragma unroll
    for (int i = 0; i < 2; ++i) {
        const int rbase = w * 8 + i * 4;
        float4 v[4];
        #pragma unroll
        for (int r = 0; r < 4; ++r)
            v[r] = ((const float4*)(emb + (size_t)(rbase + r) * DIM))[lane];
        float ss[4];
        #pragma unroll
        for (int r = 0; r < 4; ++r)
            ss[r] = v[r].x*v[r].x + v[r].y*v[r].y + v[r].z*v[r].z + v[r].w*v[r].w;
        #pragma unroll
        for (int off = 1; off < 64; off <<= 1) {
            #pragma unroll
            for (int r = 0; r < 4; ++r) ss[r] += __shfl_xor(ss[r], off);
        }
        #pragma unroll
        for (int r = 0; r < 4; ++r) {
            float inv = 1.0f / fmaxf(sqrtf(ss[r]), 1e-12f);
            ushort4 u;
            u.x = f2bf(v[r].x * inv); u.y = f2bf(v[r].y * inv);
            u.z = f2bf(v[r].z * inv); u.w = f2bf(v[r].w * inv);
            ((ushort4*)(e + (size_t)(rbase + r) * DIM))[lane] = u;
        }
    }
}

// K2 (v2, restored from R1 — v3's 4-class scan was neutral-to-worse:
// the gather/atomic path dominates, not label traffic). 2000 blocks =
// 1000 classes x 2 row-halves, ~31 waves/CU of TLP for the
// latency-bound gather while-loops.
__global__ __launch_bounds__(256) void k_gather_partial(
    const unsigned short* __restrict__ e, const int* __restrict__ labels,
    float* __restrict__ sums, unsigned int* __restrict__ counts)
{
    const int c   = blockIdx.x >> 1;       // 0..999
    const int h   = blockIdx.x & 1;        // row half
    const int tid = threadIdx.x;
    const int wave = tid >> 6, lane = tid & 63;

    __shared__ float part[4][DIM];
    __shared__ unsigned int cnt_s[4];

    const int base = h * (NROWS / 2);
    float a0 = 0.f, a1 = 0.f, a2 = 0.f, a3 = 0.f;
    unsigned int cnt = 0;

    for (int it = 0; it < (NROWS / 2) / 256 / 8; ++it) {   // 16 iterations
        int lb[8];
        #pragma unroll
        for (int u = 0; u < 8; ++u)
            lb[u] = labels[base + (it * 8 + u) * 256 + wave * 64 + lane];
        #pragma unroll
        for (int u = 0; u < 8; ++u) {
            unsigned long long m = __ballot(lb[u] == c);
            cnt += (unsigned int)__popcll(m);
            int rb = base + (it * 8 + u) * 256 + wave * 64;
            while (m) {
                int b = __ffsll((long long)m) - 1;  m &= m - 1;
                ushort4 v = ((const ushort4*)(e + (size_t)(rb + b) * DIM))[lane];
                a0 += bf2f(v.x); a1 += bf2f(v.y); a2 += bf2f(v.z); a3 += bf2f(v.w);
            }
        }
    }
    ((float4*)part[wave])[lane] = make_float4(a0, a1, a2, a3);
    if (lane == 0) cnt_s[wave] = cnt;
    __syncthreads();

    float s = part[0][tid] + part[1][tid] + part[2][tid] + part[3][tid];
    atomicAdd(&sums[(size_t)c * DIM + tid], s);
    if (tid == 0)
        atomicAdd(&counts[c], cnt_s[0] + cnt_s[1] + cnt_s[2] + cnt_s[3]);
}

// K3: one wave per class (all CPAD): center = sum/max(cnt,1), fold
// 1/max(||c||,1e-8), store bf16. Phantoms: sums=0,counts=0 -> cs=0.
__global__ __launch_bounds__(256) void k_centers(
    const float* __restrict__ sums, const unsigned int* __restrict__ counts,
    unsigned short* __restrict__ cs)
{
    int gid  = blockIdx.x * 256 + threadIdx.x;
    int c    = gid >> 6;          // wave-uniform
    int lane = gid & 63;
    float4 v = ((const float4*)(sums + (size_t)c * DIM))[lane];
    float ic = 1.0f / fmaxf((float)counts[c], 1.0f);
    v.x *= ic; v.y *= ic; v.z *= ic; v.w *= ic;
    float ss = v.x*v.x + v.y*v.y + v.z*v.z + v.w*v.w;
    #pragma unroll
    for (int off = 1; off < 64; off <<= 1) ss += __shfl_xor(ss, off);
    float sc = 1.0f / fmaxf(sqrtf(ss), 1e-8f);
    ushort4 u;
    u.x = f2bf(v.x * sc); u.y = f2bf(v.y * sc);
    u.z = f2bf(v.z * sc); u.w = f2bf(v.w * sc);
    ((ushort4*)(cs + (size_t)c * DIM))[lane] = u;
}

// K4 v9 (R16). INVERTED TILING. R15's corrected arithmetic: the
// MFMA:B-read ratio = mi (rows/wave), and every B-streaming design
// pays barriers that phase-lock waves (R10/R11). But cs is only
// 512 KB: a 128-class tile = 64 KB fits LDS WHOLE. So stage B once
// per block and stream A (e is read once per class-tile, rows split
// across waves -> zero duplication, L2-resident by XCD grouping).
//  - grid 512 = 8 class-tiles (ct) x 64 row-tiles (rt), b = ct*64+rt:
//    same-rt blocks differ by 64 -> same XCD (b%8 = rt%8) -> the 8
//    blocks sharing a row-slice (512 KB of e) share that XCD's L2.
//  - block 256 thr / 4 waves (only geometry that never spilled),
//    __launch_bounds__(256,2) -> cap 256 regs, 2 blocks/CU (LDS 64KB),
//    8 waves/CU = 2/EU.
//  - wave owns 256 rows; 4 chunks x 64 rows. Per chunk: labels(16),
//    acc[2][4][4] = 128 AGPR; per kc: A frags from global (32 VGPR,
//    transient), B from resident LDS (proven swizzle), 64 MFMA.
//  - ZERO barriers after the one staging __syncthreads. No vmcnt, no
//    sched_barrier: compiler + 2-wave TLP schedule freely.
//  - Per CU per K-step: MFMA 310 cyc > LDS 256 > A-L2 237 -> MFMA-led.
//    Floor = 2 blk x 8192 MFMA x 4.85/4 = 19.9k cyc = 8.3 us.
#define TCB4 128
#define TRB  1024
#define GRID4 (8 * 64)

__global__ __launch_bounds__(256, 2) void k_loss_mfma(
    const unsigned short* __restrict__ e, const unsigned short* __restrict__ cs,
    const int* __restrict__ labels, float* __restrict__ acc,
    unsigned int* __restrict__ done, float* __restrict__ out)
{
    __shared__ __align__(16) unsigned short b_s[4][TCB4 * 64];  // 64 KB
    __shared__ float red_s[4];

    const int tid  = threadIdx.x;
    const int ct   = blockIdx.x >> 6;          // 0..7  class tile
    const int rt   = blockIdx.x & 63;          // 0..63 row tile
    const int wave = tid >> 6, lane = tid & 63;
    const int l16 = lane & 15, q = lane >> 4;
    const int st_r = lane >> 3;                // staging row within 8-row chunk
    const int st_s = (lane & 7) ^ st_r;        // XOR-swizzled source slice

    // stage this block's 128-class B tile ONCE: 4 kc-panels x 128 rows
    #pragma unroll
    for (int kc = 0; kc < 4; ++kc)
        #pragma unroll
        for (int ch = 0; ch < 4; ++ch) {
            int c2 = wave * 4 + ch;            // 16 chunks x 8 rows = 128
            gload_lds16(&cs[(size_t)(ct*TCB4 + c2*8 + st_r) * DIM + kc*64 + st_s*8],
                        &b_s[kc][c2 * 512]);
        }
    __syncthreads();   // the ONLY barrier (drains the staging glds)

    const int rbase = rt * TRB + wave * 256;   // this wave's 256 rows
    float la_bulk = 0.0f, la_corr = 0.0f;
    const float KN = 1.0f / 999.0f;

    for (int chk = 0; chk < 4; ++chk) {        // 64-row chunks
        const int crow = rbase + chk * 64;

        int labv[16];
        #pragma unroll
        for (int mi = 0; mi < 4; ++mi)
            #pragma unroll
            for (int rg = 0; rg < 4; ++rg)
                labv[mi*4 + rg] = labels[crow + mi*16 + q*4 + rg];

        f32x4 accf[2][4][4];                   // [nh][mi][ni] = 128 AGPR
        #pragma unroll
        for (int nh = 0; nh < 2; ++nh)
            #pragma unroll
            for (int mi = 0; mi < 4; ++mi)
                #pragma unroll
                for (int ni = 0; ni < 4; ++ni)
                    accf[nh][mi][ni] = (f32x4){0.f, 0.f, 0.f, 0.f};

        #pragma unroll
        for (int kc = 0; kc < 4; ++kc) {
            bf16x8 af[4][2];                   // this kc's A frags (transient)
            #pragma unroll
            for (int mi = 0; mi < 4; ++mi) {
                const unsigned short* pa =
                    e + (size_t)(crow + mi*16 + l16) * DIM + kc*64 + q*8;
                af[mi][0] = *(const bf16x8*)pa;
                af[mi][1] = *(const bf16x8*)(pa + 32);
            }
            #pragma unroll
            for (int kk = 0; kk < 2; ++kk)
                #pragma unroll
                for (int nh = 0; nh < 2; ++nh) {
                    bf16x8 bfr[4];
                    #pragma unroll
                    for (int ni = 0; ni < 4; ++ni) {
                        int rowB = nh*64 + ni*16 + l16;
                        bfr[ni] = *(const bf16x8*)&b_s[kc][
                            rowB*64 + (((kk*4 + q) ^ (rowB & 7)) * 8)];
                    }
                    #pragma unroll
                    for (int mi = 0; mi < 4; ++mi)
                        #pragma unroll
                        for (int ni = 0; ni < 4; ++ni)
                            accf[nh][mi][ni] = __builtin_amdgcn_mfma_f32_16x16x32_bf16(
                                af[mi][kk], bfr[ni], accf[nh][mi][ni], 0, 0, 0);
                }
        }

        // epilogue: C/D col = ct*128 + nh*64 + ni*16 + l16,
        // row = crow + mi*16 + q*4 + rg. Register-only, all-static idx.
        #pragma unroll
        for (int mi = 0; mi < 4; ++mi)
            #pragma unroll
            for (int rg = 0; rg < 4; ++rg) {
                #pragma unroll
                for (int nh = 0; nh < 2; ++nh)
                    #pragma unroll
                    for (int ni = 0; ni < 4; ++ni) {
                        float t = 1.0f - accf[nh][mi][ni][rg];
                        la_bulk += t * t;
                    }
                int lr = labv[mi*4 + rg] - ct*TCB4 - l16;
                if ((lr & ~112) == 0) {        // lr in {0,16,...,112}
                    int nih = lr >> 4;         // nh*4 + ni
                    float sv = (nih & 4)
                        ? ((nih & 2) ? ((nih & 1) ? accf[1][mi][3][rg] : accf[1][mi][2][rg])
                                     : ((nih & 1) ? accf[1][mi][1][rg] : accf[1][mi][0][rg]))
                        : ((nih & 2) ? ((nih & 1) ? accf[0][mi][3][rg] : accf[0][mi][2][rg])
                                     : ((nih & 1) ? accf[0][mi][1][rg] : accf[0][mi][0][rg]));
                    float t = 1.0f - sv;
                    la_corr += t * t;
                }
            }
    }

    // block reduction + fused finalization via atomic ticket
    float la = la_bulk * KN + la_corr * (1.0f - KN);
    #pragma unroll
    for (int off = 32; off >= 1; off >>= 1) la += __shfl_xor(la, off);
    if (lane == 0) red_s[wave] = la;
    __syncthreads();
    if (tid == 0) {
        atomicAdd(acc, red_s[0] + red_s[1] + red_s[2] + red_s[3]);
        __threadfence();
        unsigned int t = atomicAdd(done, 1u);
        if (t == (unsigned int)GRID4 - 1u) {
            float v = atomicAdd(acc, 0.0f);    // atomic read: all adds visible
            out[0] = v * (1.0f / (float)NROWS) - 24.0f * (1.0f / 999.0f);
        }
    }
}

extern "C" void kernel_launch(void* const* d_in, const int* in_sizes, int n_in,
                              void* d_out, int out_size, void* d_ws, size_t ws_size,
                              hipStream_t stream)
{
    const float* emb    = (const float*)d_in[0];
    const int*   labels = (const int*)d_in[1];
    float*       out    = (float*)d_out;
    char*        ws     = (char*)d_ws;

    const size_t OFF_CS   = (size_t)NROWS * DIM * 2;            // e: 32 MB
    const size_t OFF_SUMS = OFF_CS + (size_t)CPAD * DIM * 2;    // cs: 512 KB
    const size_t OFF_CNT  = OFF_SUMS + (size_t)CPAD * DIM * 4;  // sums: 1 MB
    const size_t OFF_ACC  = OFF_CNT + (size_t)CPAD * 4;         // counts: 4 KB
    const size_t OFF_DONE = OFF_ACC + 16;

    unsigned short* e      = (unsigned short*)ws;
    unsigned short* cs     = (unsigned short*)(ws + OFF_CS);
    float*          sums   = (float*)(ws + OFF_SUMS);
    unsigned int*   counts = (unsigned int*)(ws + OFF_CNT);
    float*          acc    = (float*)(ws + OFF_ACC);
    unsigned int*   done   = (unsigned int*)(ws + OFF_DONE);

    k_norm_acc      <<<NROWS / 32, 256, 0, stream>>>(emb, e, sums, counts, acc, done);
    k_gather_partial<<<NCLS * 2, 256, 0, stream>>>(e, labels, sums, counts);
    k_centers       <<<CPAD / 4, 256, 0, stream>>>(sums, counts, cs);
    k_loss_mfma     <<<GRID4, 256, 0, stream>>>(e, cs, labels, acc, done, out);
}

// Round 8
// 243.664 us; speedup vs baseline: 1.0424x; 1.0424x over previous
//
#include <hip/hip_runtime.h>
#include <hip/hip_bf16.h>

#define NROWS 65536
#define DIM   256
#define NCLS  1000
#define CPAD  1024

typedef __attribute__((ext_vector_type(8))) short bf16x8;   // 8 bf16 = 4 VGPR
typedef __attribute__((ext_vector_type(4))) float f32x4;    // MFMA C/D

// RTNE float -> bf16 bit pattern (finite inputs only)
__device__ inline unsigned short f2bf(float x) {
    unsigned int u = __builtin_bit_cast(unsigned int, x);
    unsigned int lsb = (u >> 16) & 1u;
    u += 0x7fffu + lsb;
    return (unsigned short)(u >> 16);
}

__device__ inline float bf2f(unsigned short u) {
    unsigned int v = ((unsigned int)u) << 16;
    return __builtin_bit_cast(float, v);
}

// async global->LDS, 16 B per lane, dst = wave-uniform base + lane*16
__device__ inline void gload_lds16(const void* g, void* l) {
    __builtin_amdgcn_global_load_lds(
        (const __attribute__((address_space(1))) unsigned int*)g,
        (__attribute__((address_space(3))) unsigned int*)l, 16, 0, 0);
}

// K1: 8 rows per wave, 4-row batched pipeline (R9). Also zeroes the
// sums/counts/acc/done scratch (stream-ordered before K2 needs it).
__global__ __launch_bounds__(256) void k_norm_acc(
    const float* __restrict__ emb, unsigned short* __restrict__ e,
    float* __restrict__ sums, unsigned int* __restrict__ counts,
    float* __restrict__ acc, unsigned int* __restrict__ done)
{
    const int tid = threadIdx.x;
    const int bid = blockIdx.x;
    // zero scratch: 2048 blocks x 128 floats = CPAD*DIM sums
    if (tid < 128) sums[bid * 128 + tid] = 0.0f;
    if (bid < 16 && tid < 64) counts[bid * 64 + tid] = 0u;   // 1024 counts
    if (bid == 0 && tid == 0) { *acc = 0.0f; *done = 0u; }

    const int wave = tid >> 6, lane = tid & 63;
    const int w = bid * 4 + wave;                 // 8192 waves, 8 rows each

    #pragma unroll
    for (int i = 0; i < 2; ++i) {
        const int rbase = w * 8 + i * 4;
        float4 v[4];
        #pragma unroll
        for (int r = 0; r < 4; ++r)
            v[r] = ((const float4*)(emb + (size_t)(rbase + r) * DIM))[lane];
        float ss[4];
        #pragma unroll
        for (int r = 0; r < 4; ++r)
            ss[r] = v[r].x*v[r].x + v[r].y*v[r].y + v[r].z*v[r].z + v[r].w*v[r].w;
        #pragma unroll
        for (int off = 1; off < 64; off <<= 1) {
            #pragma unroll
            for (int r = 0; r < 4; ++r) ss[r] += __shfl_xor(ss[r], off);
        }
        #pragma unroll
        for (int r = 0; r < 4; ++r) {
            float inv = 1.0f / fmaxf(sqrtf(ss[r]), 1e-12f);
            ushort4 u;
            u.x = f2bf(v[r].x * inv); u.y = f2bf(v[r].y * inv);
            u.z = f2bf(v[r].z * inv); u.w = f2bf(v[r].w * inv);
            ((ushort4*)(e + (size_t)(rbase + r) * DIM))[lane] = u;
        }
    }
}

// K2 (v2, R1-proven): 2000 blocks = 1000 classes x 2 row-halves,
// ~31 waves/CU of TLP for the latency-bound gather while-loops.
__global__ __launch_bounds__(256) void k_gather_partial(
    const unsigned short* __restrict__ e, const int* __restrict__ labels,
    float* __restrict__ sums, unsigned int* __restrict__ counts)
{
    const int c   = blockIdx.x >> 1;       // 0..999
    const int h   = blockIdx.x & 1;        // row half
    const int tid = threadIdx.x;
    const int wave = tid >> 6, lane = tid & 63;

    __shared__ float part[4][DIM];
    __shared__ unsigned int cnt_s[4];

    const int base = h * (NROWS / 2);
    float a0 = 0.f, a1 = 0.f, a2 = 0.f, a3 = 0.f;
    unsigned int cnt = 0;

    for (int it = 0; it < (NROWS / 2) / 256 / 8; ++it) {   // 16 iterations
        int lb[8];
        #pragma unroll
        for (int u = 0; u < 8; ++u)
            lb[u] = labels[base + (it * 8 + u) * 256 + wave * 64 + lane];
        #pragma unroll
        for (int u = 0; u < 8; ++u) {
            unsigned long long m = __ballot(lb[u] == c);
            cnt += (unsigned int)__popcll(m);
            int rb = base + (it * 8 + u) * 256 + wave * 64;
            while (m) {
                int b = __ffsll((long long)m) - 1;  m &= m - 1;
                ushort4 v = ((const ushort4*)(e + (size_t)(rb + b) * DIM))[lane];
                a0 += bf2f(v.x); a1 += bf2f(v.y); a2 += bf2f(v.z); a3 += bf2f(v.w);
            }
        }
    }
    ((float4*)part[wave])[lane] = make_float4(a0, a1, a2, a3);
    if (lane == 0) cnt_s[wave] = cnt;
    __syncthreads();

    float s = part[0][tid] + part[1][tid] + part[2][tid] + part[3][tid];
    atomicAdd(&sums[(size_t)c * DIM + tid], s);
    if (tid == 0)
        atomicAdd(&counts[c], cnt_s[0] + cnt_s[1] + cnt_s[2] + cnt_s[3]);
}

// K3: one wave per class (all CPAD): center = sum/max(cnt,1), fold
// 1/max(||c||,1e-8), store bf16. Phantoms: sums=0,counts=0 -> cs=0.
__global__ __launch_bounds__(256) void k_centers(
    const float* __restrict__ sums, const unsigned int* __restrict__ counts,
    unsigned short* __restrict__ cs)
{
    int gid  = blockIdx.x * 256 + threadIdx.x;
    int c    = gid >> 6;          // wave-uniform
    int lane = gid & 63;
    float4 v = ((const float4*)(sums + (size_t)c * DIM))[lane];
    float ic = 1.0f / fmaxf((float)counts[c], 1.0f);
    v.x *= ic; v.y *= ic; v.z *= ic; v.w *= ic;
    float ss = v.x*v.x + v.y*v.y + v.z*v.z + v.w*v.w;
    #pragma unroll
    for (int off = 1; off < 64; off <<= 1) ss += __shfl_xor(ss, off);
    float sc = 1.0f / fmaxf(sqrtf(ss), 1e-8f);
    ushort4 u;
    u.x = f2bf(v.x * sc); u.y = f2bf(v.y * sc);
    u.z = f2bf(v.z * sc); u.w = f2bf(v.w * sc);
    ((ushort4*)(cs + (size_t)c * DIM))[lane] = u;
}

// K4 v10 (R17). Inverted tiling (R16 theory) in the 64-AGPR shape.
// R16 spilled because accf[2][4][4]=128 AGPR + ~110 VGPR > the 256-reg
// cap at 2 waves/EU (reported 128 VGPR + 128 AGPR + 122 MB scratch).
// Session register rule: 64-AGPR acc + <=~120 VGPR (R1's 108+64=172)
// is the proven-safe envelope. So the wave now processes 32 rows x 128
// classes per chunk (mi=2, ni=8): accf[2][8]=64 AGPR, af[2][2]=16,
// bfr[8]=32 transient, labv[8], addressing ~35 -> ~175 total.
//  - grid 512 = 8 class-tiles (ct) x 64 row-tiles (rt), b = ct*64+rt:
//    same-rt blocks land on one XCD (b%8=rt%8) sharing the 512 KB
//    A-slice in its L2.
//  - block 256 thr / 4 waves, (256,2) -> 2 blocks/CU (64 KB LDS each),
//    8 waves/CU = 2/EU.
//  - B tile (128 classes, all K) staged ONCE via glds+XOR-swizzle;
//    ONE __syncthreads total; ZERO barriers/vmcnt/sched_barriers after.
//  - A read straight from global, each element exactly once per block
//    (af per (chunk,kc), reused across kk and all 8 ni).
//  - Ceiling: A-from-L2 ~17.5k cyc, LDS-B 16.4k cyc, MFMA 9.9k cyc
//    (per CU) -> ~7-9 us overlapped.
#define TCB4 128
#define TRB  1024
#define GRID4 (8 * 64)

__global__ __launch_bounds__(256, 2) void k_loss_mfma(
    const unsigned short* __restrict__ e, const unsigned short* __restrict__ cs,
    const int* __restrict__ labels, float* __restrict__ acc,
    unsigned int* __restrict__ done, float* __restrict__ out)
{
    __shared__ __align__(16) unsigned short b_s[4][TCB4 * 64];  // 64 KB
    __shared__ float red_s[4];

    const int tid  = threadIdx.x;
    const int ct   = blockIdx.x >> 6;          // 0..7  class tile
    const int rt   = blockIdx.x & 63;          // 0..63 row tile
    const int wave = tid >> 6, lane = tid & 63;
    const int l16 = lane & 15, q = lane >> 4;
    const int st_r = lane >> 3;                // staging row within 8-row chunk
    const int st_s = (lane & 7) ^ st_r;        // XOR-swizzled source slice

    // stage this block's 128-class B tile ONCE: 4 kc-panels x 128 rows
    #pragma unroll
    for (int kc = 0; kc < 4; ++kc)
        #pragma unroll
        for (int ch = 0; ch < 4; ++ch) {
            int c2 = wave * 4 + ch;            // 16 chunks x 8 rows = 128
            gload_lds16(&cs[(size_t)(ct*TCB4 + c2*8 + st_r) * DIM + kc*64 + st_s*8],
                        &b_s[kc][c2 * 512]);
        }
    __syncthreads();   // the ONLY barrier (drains the staging glds)

    const int rbase = rt * TRB + wave * 256;   // this wave's 256 rows
    float la_bulk = 0.0f, la_corr = 0.0f;
    const float KN = 1.0f / 999.0f;

    for (int chk = 0; chk < 8; ++chk) {        // 32-row chunks
        const int crow = rbase + chk * 32;

        int labv[8];
        #pragma unroll
        for (int mi = 0; mi < 2; ++mi)
            #pragma unroll
            for (int rg = 0; rg < 4; ++rg)
                labv[mi*4 + rg] = labels[crow + mi*16 + q*4 + rg];

        f32x4 accf[2][8];                      // 64 AGPR
        #pragma unroll
        for (int mi = 0; mi < 2; ++mi)
            #pragma unroll
            for (int ni = 0; ni < 8; ++ni)
                accf[mi][ni] = (f32x4){0.f, 0.f, 0.f, 0.f};

        #pragma unroll
        for (int kc = 0; kc < 4; ++kc) {
            bf16x8 af[2][2];                   // this kc's A frags (transient)
            #pragma unroll
            for (int mi = 0; mi < 2; ++mi) {
                const unsigned short* pa =
                    e + (size_t)(crow + mi*16 + l16) * DIM + kc*64 + q*8;
                af[mi][0] = *(const bf16x8*)pa;
                af[mi][1] = *(const bf16x8*)(pa + 32);
            }
            #pragma unroll
            for (int kk = 0; kk < 2; ++kk) {
                bf16x8 bfr[8];
                #pragma unroll
                for (int ni = 0; ni < 8; ++ni) {
                    int rowB = ni*16 + l16;
                    bfr[ni] = *(const bf16x8*)&b_s[kc][
                        rowB*64 + (((kk*4 + q) ^ (rowB & 7)) * 8)];
                }
                #pragma unroll
                for (int mi = 0; mi < 2; ++mi)
                    #pragma unroll
                    for (int ni = 0; ni < 8; ++ni)
                        accf[mi][ni] = __builtin_amdgcn_mfma_f32_16x16x32_bf16(
                            af[mi][kk], bfr[ni], accf[mi][ni], 0, 0, 0);
            }
        }

        // epilogue: C/D col = ct*128 + ni*16 + l16,
        // row = crow + mi*16 + q*4 + rg. Register-only, all-static idx.
        #pragma unroll
        for (int mi = 0; mi < 2; ++mi)
            #pragma unroll
            for (int rg = 0; rg < 4; ++rg) {
                #pragma unroll
                for (int ni = 0; ni < 8; ++ni) {
                    float t = 1.0f - accf[mi][ni][rg];
                    la_bulk += t * t;
                }
                int lr = labv[mi*4 + rg] - ct*TCB4 - l16;
                if ((lr & ~112) == 0) {        // lr in {0,16,...,112}
                    int nih = lr >> 4;
                    float sv = (nih & 4)
                        ? ((nih & 2) ? ((nih & 1) ? accf[mi][7][rg] : accf[mi][6][rg])
                                     : ((nih & 1) ? accf[mi][5][rg] : accf[mi][4][rg]))
                        : ((nih & 2) ? ((nih & 1) ? accf[mi][3][rg] : accf[mi][2][rg])
                                     : ((nih & 1) ? accf[mi][1][rg] : accf[mi][0][rg]));
                    float t = 1.0f - sv;
                    la_corr += t * t;
                }
            }
    }

    // block reduction + fused finalization via atomic ticket
    float la = la_bulk * KN + la_corr * (1.0f - KN);
    #pragma unroll
    for (int off = 32; off >= 1; off >>= 1) la += __shfl_xor(la, off);
    if (lane == 0) red_s[wave] = la;
    __syncthreads();
    if (tid == 0) {
        atomicAdd(acc, red_s[0] + red_s[1] + red_s[2] + red_s[3]);
        __threadfence();
        unsigned int t = atomicAdd(done, 1u);
        if (t == (unsigned int)GRID4 - 1u) {
            float v = atomicAdd(acc, 0.0f);    // atomic read: all adds visible
            out[0] = v * (1.0f / (float)NROWS) - 24.0f * (1.0f / 999.0f);
        }
    }
}

extern "C" void kernel_launch(void* const* d_in, const int* in_sizes, int n_in,
                              void* d_out, int out_size, void* d_ws, size_t ws_size,
                              hipStream_t stream)
{
    const float* emb    = (const float*)d_in[0];
    const int*   labels = (const int*)d_in[1];
    float*       out    = (float*)d_out;
    char*        ws     = (char*)d_ws;

    const size_t OFF_CS   = (size_t)NROWS * DIM * 2;            // e: 32 MB
    const size_t OFF_SUMS = OFF_CS + (size_t)CPAD * DIM * 2;    // cs: 512 KB
    const size_t OFF_CNT  = OFF_SUMS + (size_t)CPAD * DIM * 4;  // sums: 1 MB
    const size_t OFF_ACC  = OFF_CNT + (size_t)CPAD * 4;         // counts: 4 KB
    const size_t OFF_DONE = OFF_ACC + 16;

    unsigned short* e      = (unsigned short*)ws;
    unsigned short* cs     = (unsigned short*)(ws + OFF_CS);
    float*          sums   = (float*)(ws + OFF_SUMS);
    unsigned int*   counts = (unsigned int*)(ws + OFF_CNT);
    float*          acc    = (float*)(ws + OFF_ACC);
    unsigned int*   done   = (unsigned int*)(ws + OFF_DONE);

    k_norm_acc      <<<NROWS / 32, 256, 0, stream>>>(emb, e, sums, counts, acc, done);
    k_gather_partial<<<NCLS * 2, 256, 0, stream>>>(e, labels, sums, counts);
    k_centers       <<<CPAD / 4, 256, 0, stream>>>(sums, counts, cs);
    k_loss_mfma     <<<GRID4, 256, 0, stream>>>(e, cs, labels, acc, done, out);
}

// Round 9
// 241.968 us; speedup vs baseline: 1.0497x; 1.0070x over previous
//
#include <hip/hip_runtime.h>
#include <hip/hip_bf16.h>

#define NROWS 65536
#define DIM   256
#define NCLS  1000
#define CPAD  1024

typedef __attribute__((ext_vector_type(8))) short bf16x8;   // 8 bf16 = 4 VGPR
typedef __attribute__((ext_vector_type(4))) float f32x4;    // MFMA C/D

// RTNE float -> bf16 bit pattern (finite inputs only)
__device__ inline unsigned short f2bf(float x) {
    unsigned int u = __builtin_bit_cast(unsigned int, x);
    unsigned int lsb = (u >> 16) & 1u;
    u += 0x7fffu + lsb;
    return (unsigned short)(u >> 16);
}

__device__ inline float bf2f(unsigned short u) {
    unsigned int v = ((unsigned int)u) << 16;
    return __builtin_bit_cast(float, v);
}

// async global->LDS, 16 B per lane, dst = wave-uniform base + lane*16
__device__ inline void gload_lds16(const void* g, void* l) {
    __builtin_amdgcn_global_load_lds(
        (const __attribute__((address_space(1))) unsigned int*)g,
        (__attribute__((address_space(3))) unsigned int*)l, 16, 0, 0);
}

// K1: 8 rows per wave, 4-row batched pipeline (R9). Also zeroes the
// sums/counts/acc/done scratch (stream-ordered before K2 needs it).
__global__ __launch_bounds__(256) void k_norm_acc(
    const float* __restrict__ emb, unsigned short* __restrict__ e,
    float* __restrict__ sums, unsigned int* __restrict__ counts,
    float* __restrict__ acc, unsigned int* __restrict__ done)
{
    const int tid = threadIdx.x;
    const int bid = blockIdx.x;
    // zero scratch: 2048 blocks x 128 floats = CPAD*DIM sums
    if (tid < 128) sums[bid * 128 + tid] = 0.0f;
    if (bid < 16 && tid < 64) counts[bid * 64 + tid] = 0u;   // 1024 counts
    if (bid == 0 && tid == 0) { *acc = 0.0f; *done = 0u; }

    const int wave = tid >> 6, lane = tid & 63;
    const int w = bid * 4 + wave;                 // 8192 waves, 8 rows each

    #pragma unroll
    for (int i = 0; i < 2; ++i) {
        const int rbase = w * 8 + i * 4;
        float4 v[4];
        #pragma unroll
        for (int r = 0; r < 4; ++r)
            v[r] = ((const float4*)(emb + (size_t)(rbase + r) * DIM))[lane];
        float ss[4];
        #pragma unroll
        for (int r = 0; r < 4; ++r)
            ss[r] = v[r].x*v[r].x + v[r].y*v[r].y + v[r].z*v[r].z + v[r].w*v[r].w;
        #pragma unroll
        for (int off = 1; off < 64; off <<= 1) {
            #pragma unroll
            for (int r = 0; r < 4; ++r) ss[r] += __shfl_xor(ss[r], off);
        }
        #pragma unroll
        for (int r = 0; r < 4; ++r) {
            float inv = 1.0f / fmaxf(sqrtf(ss[r]), 1e-12f);
            ushort4 u;
            u.x = f2bf(v[r].x * inv); u.y = f2bf(v[r].y * inv);
            u.z = f2bf(v[r].z * inv); u.w = f2bf(v[r].w * inv);
            ((ushort4*)(e + (size_t)(rbase + r) * DIM))[lane] = u;
        }
    }
}

// K2 (v2, R1-proven): 2000 blocks = 1000 classes x 2 row-halves,
// ~31 waves/CU of TLP for the latency-bound gather while-loops.
__global__ __launch_bounds__(256) void k_gather_partial(
    const unsigned short* __restrict__ e, const int* __restrict__ labels,
    float* __restrict__ sums, unsigned int* __restrict__ counts)
{
    const int c   = blockIdx.x >> 1;       // 0..999
    const int h   = blockIdx.x & 1;        // row half
    const int tid = threadIdx.x;
    const int wave = tid >> 6, lane = tid & 63;

    __shared__ float part[4][DIM];
    __shared__ unsigned int cnt_s[4];

    const int base = h * (NROWS / 2);
    float a0 = 0.f, a1 = 0.f, a2 = 0.f, a3 = 0.f;
    unsigned int cnt = 0;

    for (int it = 0; it < (NROWS / 2) / 256 / 8; ++it) {   // 16 iterations
        int lb[8];
        #pragma unroll
        for (int u = 0; u < 8; ++u)
            lb[u] = labels[base + (it * 8 + u) * 256 + wave * 64 + lane];
        #pragma unroll
        for (int u = 0; u < 8; ++u) {
            unsigned long long m = __ballot(lb[u] == c);
            cnt += (unsigned int)__popcll(m);
            int rb = base + (it * 8 + u) * 256 + wave * 64;
            while (m) {
                int b = __ffsll((long long)m) - 1;  m &= m - 1;
                ushort4 v = ((const ushort4*)(e + (size_t)(rb + b) * DIM))[lane];
                a0 += bf2f(v.x); a1 += bf2f(v.y); a2 += bf2f(v.z); a3 += bf2f(v.w);
            }
        }
    }
    ((float4*)part[wave])[lane] = make_float4(a0, a1, a2, a3);
    if (lane == 0) cnt_s[wave] = cnt;
    __syncthreads();

    float s = part[0][tid] + part[1][tid] + part[2][tid] + part[3][tid];
    atomicAdd(&sums[(size_t)c * DIM + tid], s);
    if (tid == 0)
        atomicAdd(&counts[c], cnt_s[0] + cnt_s[1] + cnt_s[2] + cnt_s[3]);
}

// K3: one wave per class (all CPAD): center = sum/max(cnt,1), fold
// 1/max(||c||,1e-8), store bf16. Phantoms: sums=0,counts=0 -> cs=0.
__global__ __launch_bounds__(256) void k_centers(
    const float* __restrict__ sums, const unsigned int* __restrict__ counts,
    unsigned short* __restrict__ cs)
{
    int gid  = blockIdx.x * 256 + threadIdx.x;
    int c    = gid >> 6;          // wave-uniform
    int lane = gid & 63;
    float4 v = ((const float4*)(sums + (size_t)c * DIM))[lane];
    float ic = 1.0f / fmaxf((float)counts[c], 1.0f);
    v.x *= ic; v.y *= ic; v.z *= ic; v.w *= ic;
    float ss = v.x*v.x + v.y*v.y + v.z*v.z + v.w*v.w;
    #pragma unroll
    for (int off = 1; off < 64; off <<= 1) ss += __shfl_xor(ss, off);
    float sc = 1.0f / fmaxf(sqrtf(ss), 1e-8f);
    ushort4 u;
    u.x = f2bf(v.x * sc); u.y = f2bf(v.y * sc);
    u.z = f2bf(v.z * sc); u.w = f2bf(v.w * sc);
    ((ushort4*)(cs + (size_t)c * DIM))[lane] = u;
}

// K4 v11 (R18). R17 post-mortem: v10's spill was NOT accumulator size.
// A-loads from GLOBAL inside a fully-unrollable 8-chunk loop -> LLVM
// scheduler hoists loads across chunks to hide ~200-900cy latency ->
// live-range explosion -> spill (63 MB scratch), and the scratch
// working set thrashed L2, destroying the e-slice sharing (270 MB HBM
// fetch, memory-bound). Two bounded fixes, same structure:
//  1. #pragma clang loop unroll(disable) on the chk loop: the
//     scheduler cannot hoist loads across a non-unrolled runtime loop,
//     so the live set is bounded by ONE chunk body.
//  2. A loaded per-chunk ALL-kc upfront into af[4][2][2] (64 VGPR,
//     explicit bound): kc>0 loads hide under kc=0 MFMAs via the
//     compiler's counted vmcnt waits -- the latency hiding the
//     scheduler wants, without it inventing its own.
// Live set: accf 64 (AGPR) + af 64 + bfr 32 + labv 8 + misc ~45 =
// ~215 < 256-reg cap at 2 waves/EU.
// Structure (unchanged from v10): grid 512 = 8 ct x 64 rt (same-rt
// blocks share an XCD's L2 for the 512 KB e-slice); 256 thr / 4 waves,
// (256,2) -> 2 blocks/CU; B tile (128 classes, all K) staged once via
// glds+XOR-swizzle; ONE __syncthreads; zero barriers after.
#define TCB4 128
#define TRB  1024
#define GRID4 (8 * 64)

__global__ __launch_bounds__(256, 2) void k_loss_mfma(
    const unsigned short* __restrict__ e, const unsigned short* __restrict__ cs,
    const int* __restrict__ labels, float* __restrict__ acc,
    unsigned int* __restrict__ done, float* __restrict__ out)
{
    __shared__ __align__(16) unsigned short b_s[4][TCB4 * 64];  // 64 KB
    __shared__ float red_s[4];

    const int tid  = threadIdx.x;
    const int ct   = blockIdx.x >> 6;          // 0..7  class tile
    const int rt   = blockIdx.x & 63;          // 0..63 row tile
    const int wave = tid >> 6, lane = tid & 63;
    const int l16 = lane & 15, q = lane >> 4;
    const int st_r = lane >> 3;                // staging row within 8-row chunk
    const int st_s = (lane & 7) ^ st_r;        // XOR-swizzled source slice

    // stage this block's 128-class B tile ONCE: 4 kc-panels x 128 rows
    #pragma unroll
    for (int kc = 0; kc < 4; ++kc)
        #pragma unroll
        for (int ch = 0; ch < 4; ++ch) {
            int c2 = wave * 4 + ch;            // 16 chunks x 8 rows = 128
            gload_lds16(&cs[(size_t)(ct*TCB4 + c2*8 + st_r) * DIM + kc*64 + st_s*8],
                        &b_s[kc][c2 * 512]);
        }
    __syncthreads();   // the ONLY barrier (drains the staging glds)

    const int rbase = rt * TRB + wave * 256;   // this wave's 256 rows
    float la_bulk = 0.0f, la_corr = 0.0f;
    const float KN = 1.0f / 999.0f;

    #pragma clang loop unroll(disable)
    for (int chk = 0; chk < 8; ++chk) {        // 32-row chunks, NOT unrolled
        const int crow = rbase + chk * 32;

        // A for the whole chunk (all kc), explicit bounded prefetch:
        // 16 x 16B loads issued upfront; kc>0 hides under kc=0 MFMAs.
        bf16x8 af[4][2][2];
        #pragma unroll
        for (int kc = 0; kc < 4; ++kc)
            #pragma unroll
            for (int mi = 0; mi < 2; ++mi) {
                const unsigned short* pa =
                    e + (size_t)(crow + mi*16 + l16) * DIM + kc*64 + q*8;
                af[kc][mi][0] = *(const bf16x8*)pa;
                af[kc][mi][1] = *(const bf16x8*)(pa + 32);
            }

        int labv[8];
        #pragma unroll
        for (int mi = 0; mi < 2; ++mi)
            #pragma unroll
            for (int rg = 0; rg < 4; ++rg)
                labv[mi*4 + rg] = labels[crow + mi*16 + q*4 + rg];

        f32x4 accf[2][8];                      // 64 AGPR
        #pragma unroll
        for (int mi = 0; mi < 2; ++mi)
            #pragma unroll
            for (int ni = 0; ni < 8; ++ni)
                accf[mi][ni] = (f32x4){0.f, 0.f, 0.f, 0.f};

        #pragma unroll
        for (int kc = 0; kc < 4; ++kc) {
            #pragma unroll
            for (int kk = 0; kk < 2; ++kk) {
                bf16x8 bfr[8];
                #pragma unroll
                for (int ni = 0; ni < 8; ++ni) {
                    int rowB = ni*16 + l16;
                    bfr[ni] = *(const bf16x8*)&b_s[kc][
                        rowB*64 + (((kk*4 + q) ^ (rowB & 7)) * 8)];
                }
                #pragma unroll
                for (int mi = 0; mi < 2; ++mi)
                    #pragma unroll
                    for (int ni = 0; ni < 8; ++ni)
                        accf[mi][ni] = __builtin_amdgcn_mfma_f32_16x16x32_bf16(
                            af[kc][mi][kk], bfr[ni], accf[mi][ni], 0, 0, 0);
            }
        }

        // epilogue: C/D col = ct*128 + ni*16 + l16,
        // row = crow + mi*16 + q*4 + rg. Register-only, all-static idx.
        #pragma unroll
        for (int mi = 0; mi < 2; ++mi)
            #pragma unroll
            for (int rg = 0; rg < 4; ++rg) {
                #pragma unroll
                for (int ni = 0; ni < 8; ++ni) {
                    float t = 1.0f - accf[mi][ni][rg];
                    la_bulk += t * t;
                }
                int lr = labv[mi*4 + rg] - ct*TCB4 - l16;
                if ((lr & ~112) == 0) {        // lr in {0,16,...,112}
                    int nih = lr >> 4;
                    float sv = (nih & 4)
                        ? ((nih & 2) ? ((nih & 1) ? accf[mi][7][rg] : accf[mi][6][rg])
                                     : ((nih & 1) ? accf[mi][5][rg] : accf[mi][4][rg]))
                        : ((nih & 2) ? ((nih & 1) ? accf[mi][3][rg] : accf[mi][2][rg])
                                     : ((nih & 1) ? accf[mi][1][rg] : accf[mi][0][rg]));
                    float t = 1.0f - sv;
                    la_corr += t * t;
                }
            }
    }

    // block reduction + fused finalization via atomic ticket
    float la = la_bulk * KN + la_corr * (1.0f - KN);
    #pragma unroll
    for (int off = 32; off >= 1; off >>= 1) la += __shfl_xor(la, off);
    if (lane == 0) red_s[wave] = la;
    __syncthreads();
    if (tid == 0) {
        atomicAdd(acc, red_s[0] + red_s[1] + red_s[2] + red_s[3]);
        __threadfence();
        unsigned int t = atomicAdd(done, 1u);
        if (t == (unsigned int)GRID4 - 1u) {
            float v = atomicAdd(acc, 0.0f);    // atomic read: all adds visible
            out[0] = v * (1.0f / (float)NROWS) - 24.0f * (1.0f / 999.0f);
        }
    }
}

extern "C" void kernel_launch(void* const* d_in, const int* in_sizes, int n_in,
                              void* d_out, int out_size, void* d_ws, size_t ws_size,
                              hipStream_t stream)
{
    const float* emb    = (const float*)d_in[0];
    const int*   labels = (const int*)d_in[1];
    float*       out    = (float*)d_out;
    char*        ws     = (char*)d_ws;

    const size_t OFF_CS   = (size_t)NROWS * DIM * 2;            // e: 32 MB
    const size_t OFF_SUMS = OFF_CS + (size_t)CPAD * DIM * 2;    // cs: 512 KB
    const size_t OFF_CNT  = OFF_SUMS + (size_t)CPAD * DIM * 4;  // sums: 1 MB
    const size_t OFF_ACC  = OFF_CNT + (size_t)CPAD * 4;         // counts: 4 KB
    const size_t OFF_DONE = OFF_ACC + 16;

    unsigned short* e      = (unsigned short*)ws;
    unsigned short* cs     = (unsigned short*)(ws + OFF_CS);
    float*          sums   = (float*)(ws + OFF_SUMS);
    unsigned int*   counts = (unsigned int*)(ws + OFF_CNT);
    float*          acc    = (float*)(ws + OFF_ACC);
    unsigned int*   done   = (unsigned int*)(ws + OFF_DONE);

    k_norm_acc      <<<NROWS / 32, 256, 0, stream>>>(emb, e, sums, counts, acc, done);
    k_gather_partial<<<NCLS * 2, 256, 0, stream>>>(e, labels, sums, counts);
    k_centers       <<<CPAD / 4, 256, 0, stream>>>(sums, counts, cs);
    k_loss_mfma     <<<GRID4, 256, 0, stream>>>(e, cs, labels, acc, done, out);
}